// Round 16
// baseline (312.765 us; speedup 1.0000x reference)
//
#include <hip/hip_runtime.h>
#include <hip/hip_bf16.h>

typedef __attribute__((ext_vector_type(8))) short short8;
typedef __attribute__((ext_vector_type(4))) float f32x4;

#define MFMA16(a, b, c) __builtin_amdgcn_mfma_f32_16x16x32_bf16((a), (b), (c), 0, 0, 0)

__device__ __forceinline__ unsigned short f2bf(float f) {
  union { float f; unsigned int u; } v; v.f = f;
  return (unsigned short)((v.u + 0x7fffu + ((v.u >> 16) & 1u)) >> 16);
}

__device__ __forceinline__ void gload_lds16(const void* g, void* l) {
  __builtin_amdgcn_global_load_lds((__attribute__((address_space(1))) void*)g,
                                   (__attribute__((address_space(3))) void*)l,
                                   16, 0, 0);
}

// ---------------- weight fp32 -> bf16 conversion (4 arrays in one launch) ----
struct CvtArgs {
  const float* s0; const float* s1; const float* s2; const float* s3;
  unsigned short* d0; unsigned short* d1; unsigned short* d2; unsigned short* d3;
};

__global__ __launch_bounds__(256) void cvt_weights(CvtArgs a) {
  const long N0 = 1048576, N1 = 1048576, N2 = 4194304;  // wq, wo, w1 (w2 rest)
  long i = ((long)blockIdx.x * 256 + threadIdx.x) * 4;
  const float* s; unsigned short* d; long off;
  if (i < N0)                { s = a.s0; d = a.d0; off = i; }
  else if (i < N0 + N1)      { s = a.s1; d = a.d1; off = i - N0; }
  else if (i < N0 + N1 + N2) { s = a.s2; d = a.d2; off = i - N0 - N1; }
  else                       { s = a.s3; d = a.d3; off = i - N0 - N1 - N2; }
  float4 v = *(const float4*)(s + off);
  ushort4 o;
  o.x = f2bf(v.x); o.y = f2bf(v.y); o.z = f2bf(v.z); o.w = f2bf(v.w);
  *(ushort4*)(d + off) = o;
}

// ---------------- LayerNorm (ddof=1, eps added to std), fp32 in -> bf16 out --
__global__ __launch_bounds__(256) void ln_kernel(
    const float* __restrict__ x,
    const float* __restrict__ alpha, const float* __restrict__ beta,
    unsigned short* __restrict__ out) {
  const int row = blockIdx.x;
  const int tid = threadIdx.x;
  const float4 v = ((const float4*)(x + (size_t)row * 1024))[tid];
  float s  = v.x + v.y + v.z + v.w;
  float sq = v.x * v.x + v.y * v.y + v.z * v.z + v.w * v.w;
  #pragma unroll
  for (int d = 32; d >= 1; d >>= 1) {
    s  += __shfl_xor(s, d, 64);
    sq += __shfl_xor(sq, d, 64);
  }
  __shared__ float red[8];
  const int w = tid >> 6;
  if ((tid & 63) == 0) { red[w] = s; red[4 + w] = sq; }
  __syncthreads();
  s  = red[0] + red[1] + red[2] + red[3];
  sq = red[4] + red[5] + red[6] + red[7];
  const float mean = s * (1.f / 1024.f);
  float var = (sq - s * mean) * (1.f / 1023.f);
  var = fmaxf(var, 0.f);
  const float rs = alpha[0] / (sqrtf(var) + 1e-6f);
  const float bb = beta[0];
  ushort4 o;
  o.x = f2bf((v.x - mean) * rs + bb);
  o.y = f2bf((v.y - mean) * rs + bb);
  o.z = f2bf((v.z - mean) * rs + bb);
  o.w = f2bf((v.w - mean) * rs + bb);
  ((ushort4*)out)[(size_t)row * 256 + tid] = o;
}

// ---------------- 2-phase 256xBN GEMM, C = A @ B^T + bias -------------------
// DBUF=1: double-buffered staging (1 block/CU). DBUF=0: single-buffered m97
// 2-barrier loop with LDS <= 80KB -> 2 blocks/CU co-resident; the other
// block's compute hides this block's vmcnt drain (m114 mechanism).
// bf16 out: LDS-staged coalesced epilogue (+optional fused qT transpose).
// fp32 out: LDS-staged coalesced epilogue with fused residual add.
template <int OUT_BF16, int RELU, int NF, int WQT, int DBUF>
__global__ __launch_bounds__(512, 2) void gemm2ph(
    const unsigned short* __restrict__ A, int lda,
    const unsigned short* __restrict__ B, int ldb,
    const float* __restrict__ bias,
    const float* __restrict__ residual,
    void* __restrict__ Cout,
    unsigned short* __restrict__ qTout,
    int M, int N, int K, float cscale, int nbx) {
  constexpr int STG = DBUF ? (32768 + NF * 8192) : (16384 + NF * 4096);
  constexpr int EPI = OUT_BF16 ? 128 * (NF * 64 + 4) : 256 * (NF * 64 + 4);
  constexpr int LSH = STG > EPI ? STG : EPI;
  __shared__ __align__(16) unsigned short lds[LSH];
  const int NT = K >> 6;
  const int tid = threadIdx.x;
  const int w = tid >> 6, lane = tid & 63;
  const int cpx = gridDim.x >> 3;
  const int id = (blockIdx.x & 7) * cpx + (blockIdx.x >> 3);  // XCD swizzle
  const int bx = id % nbx, by = id / nbx;
  const int row0 = by * 256, col0 = bx * (NF * 64);
  const int wr128 = (w >> 2) * 128, wcN = (w & 3) * (NF * 16);
  const int lq = lane & 15, g = lane >> 4, g4 = g * 4;
  const int strow = tid >> 3;                        // 0..63
  const int sunit8 = ((tid & 7) ^ (strow & 7)) * 8;  // inverse-swizzled k-off

  const unsigned short* Asrc = A + (size_t)(row0 + strow) * lda + sunit8;
  const unsigned short* Bsrc = B + (size_t)(col0 + strow) * ldb + sunit8;

  auto stage = [&](int buf, int tt) {
    unsigned short* Ad = lds + (DBUF ? buf * 16384 : 0) + w * 512;
    unsigned short* Bd = lds + (DBUF ? 32768 + buf * (NF * 4096) : 16384) + w * 512;
    #pragma unroll
    for (int c = 0; c < 4; ++c)
      gload_lds16(Asrc + (size_t)(c * 64) * lda + tt * 64, Ad + c * 4096);
    #pragma unroll
    for (int c = 0; c < NF; ++c)
      gload_lds16(Bsrc + (size_t)(c * 64) * ldb + tt * 64, Bd + c * 4096);
  };

  f32x4 acc[8][NF] = {};

  auto compute = [&](int buf) {
    const unsigned short* Ab = lds + (DBUF ? buf * 16384 : 0);
    const unsigned short* Bb = lds + (DBUF ? 32768 + buf * (NF * 4096) : 16384);
    #pragma unroll
    for (int kk = 0; kk < 2; ++kk) {
      short8 af[8], bf[NF];
      #pragma unroll
      for (int m = 0; m < 8; ++m) {
        const int r = wr128 + m * 16 + lq;
        af[m] = *(const short8*)(Ab + r * 64 + (((kk * 4 + g) ^ (r & 7)) << 3));
      }
      #pragma unroll
      for (int n = 0; n < NF; ++n) {
        const int r = wcN + n * 16 + lq;
        bf[n] = *(const short8*)(Bb + r * 64 + (((kk * 4 + g) ^ (r & 7)) << 3));
      }
      __builtin_amdgcn_s_setprio(1);
      #pragma unroll
      for (int m = 0; m < 8; ++m)
        #pragma unroll
        for (int n = 0; n < NF; ++n)
          acc[m][n] = MFMA16(af[m], bf[n], acc[m][n]);
      __builtin_amdgcn_s_setprio(0);
    }
  };

  if (DBUF) {
    stage(0, 0);
    asm volatile("s_waitcnt vmcnt(0)" ::: "memory");
    __builtin_amdgcn_s_barrier();
    int buf = 0;
    for (int t = 0; t < NT; ++t) {
      if (t + 1 < NT) stage(buf ^ 1, t + 1);
      compute(buf);
      if (t + 1 < NT) {
        asm volatile("s_waitcnt vmcnt(0)" ::: "memory");
        __builtin_amdgcn_s_barrier();
        buf ^= 1;
      }
    }
  } else {
    // single-buffer m97 2-barrier loop; 2 blocks/CU hide each other's drain
    for (int t = 0; t < NT; ++t) {
      __syncthreads();
      stage(0, t);
      asm volatile("s_waitcnt vmcnt(0)" ::: "memory");
      __syncthreads();
      compute(0);
    }
  }

  // ---- epilogue ----
  float bv[NF];
  #pragma unroll
  for (int n = 0; n < NF; ++n) bv[n] = bias[col0 + wcN + n * 16 + lq];

  if (OUT_BF16) {
    // stage C tile through LDS (padded stride), coalesced row copies
    const int CW = NF * 64 + 4;
    unsigned short* cbuf = lds;
    __syncthreads();
    #pragma unroll
    for (int p = 0; p < 2; ++p) {
      if ((w >> 2) == p) {
        #pragma unroll
        for (int m = 0; m < 8; ++m)
          #pragma unroll
          for (int n = 0; n < NF; ++n)
            #pragma unroll
            for (int r = 0; r < 4; ++r) {
              float v = (acc[m][n][r] + bv[n]) * cscale;
              if (RELU) v = fmaxf(v, 0.f);
              cbuf[(m * 16 + g4 + r) * CW + wcN + n * 16 + lq] = f2bf(v);
            }
      }
      __syncthreads();
      #pragma unroll
      for (int i = 0; i < 2 * NF; ++i) {
        const int un = i * 512 + tid;
        const int row = un / (8 * NF);
        const int cu = un % (8 * NF);
        const short8 vv = *(const short8*)&cbuf[row * CW + cu * 8];
        *(short8*)((unsigned short*)Cout + (size_t)(row0 + p * 128 + row) * N + col0 + cu * 8) = vv;
      }
      if (WQT) {
        // fused transpose: qT[bh][d][s], 128 cols x 128 s from this half-tile
        const int grow = row0 + p * 128;
        const int bb = grow >> 10;
        const int s0 = grow & 1023;
        const int h0 = col0 >> 6;
        #pragma unroll
        for (int i = 0; i < 4; ++i) {
          const int un = i * 512 + tid;        // 2048 = 128 cols x 16 s-units
          const int colx = un >> 4;
          const int su = un & 15;
          const int hh = h0 + (colx >> 6);
          const int dd = colx & 63;
          short8 o;
          #pragma unroll
          for (int j = 0; j < 8; ++j) o[j] = (short)cbuf[(su * 8 + j) * CW + colx];
          *(short8*)(qTout + ((size_t)(bb * 16 + hh) * 64 + dd) * 1024 + s0 + su * 8) = o;
        }
      }
      __syncthreads();
    }
  } else {
    // fp32: stage half-tile in LDS, coalesced float4 rows + fused residual
    const int CWf = NF * 64 + 4;
    float* cbuf = (float*)lds;
    __syncthreads();
    #pragma unroll
    for (int p = 0; p < 2; ++p) {
      if ((w >> 2) == p) {
        #pragma unroll
        for (int m = 0; m < 8; ++m)
          #pragma unroll
          for (int n = 0; n < NF; ++n)
            #pragma unroll
            for (int r = 0; r < 4; ++r) {
              float v = (acc[m][n][r] + bv[n]) * cscale;
              if (RELU) v = fmaxf(v, 0.f);
              cbuf[(m * 16 + g4 + r) * CWf + wcN + n * 16 + lq] = v;
            }
      }
      __syncthreads();
      #pragma unroll
      for (int i = 0; i < 4 * NF; ++i) {
        const int un = i * 512 + tid;            // rows x (NF*16) float4 units
        const int row = un / (16 * NF);
        const int cu = un % (16 * NF);
        float4 v = *(const float4*)&cbuf[row * CWf + cu * 4];
        const size_t idx = (size_t)(row0 + p * 128 + row) * N + col0 + cu * 4;
        if (residual) {
          const float4 rv = *(const float4*)(residual + idx);
          v.x += rv.x; v.y += rv.y; v.z += rv.z; v.w += rv.w;
        }
        *(float4*)((float*)Cout + idx) = v;
      }
      __syncthreads();
    }
  }
}

// ---------------- flash attention v9: no-max softmax (bounded domain) --------
__global__ __launch_bounds__(256) void attn_kernel(
    const unsigned short* __restrict__ q,    // [B,S,1024] bf16 (scaled)
    const unsigned short* __restrict__ qT,   // [B*H,64,1024] bf16 (scaled)
    const int* __restrict__ mask,            // [B,1024]
    unsigned short* __restrict__ ctx) {      // [B,S,1024] bf16
  __shared__ __align__(16) unsigned short Ks[2][64 * 64];
  __shared__ __align__(16) unsigned short Vs[2][64 * 64];
  __shared__ int allmask;
  const int id = blockIdx.x;
  const int bh = ((id & 7) << 4) + (id >> 6);      // same-XCD blocks share bh set
  const int qt = (id >> 3) & 7;
  const int b = bh >> 4, h = bh & 15;
  const int tid = threadIdx.x, w = tid >> 6, lane = tid & 63;
  const int lq = lane & 15;
  const int g = lane >> 4;
  const int lk8 = g * 8;
  const int swz = lane & 7;
  const int q0 = qt * 128 + w * 32;
  const size_t qbase = (size_t)b * (1024 * 1024) + h * 64;
  const size_t qTb = (size_t)bh * 64 * 1024;
  const int srow = lane >> 3;                      // 0..7
  const int su = (lane & 7) ^ srow;                // inverse-swizzled unit
  const size_t ksrc = qbase + (size_t)(w * 16 + srow) * 1024 + su * 8;
  const size_t vsrc = qTb + (size_t)(w * 16 + srow) * 1024 + su * 8;
  const float RS = 2.3548202f;                     // 1/sqrt(0.125*log2e)

  auto stage = [&](int bufi, int kt) {
    char* Kd = (char*)Ks[bufi] + w * 2048;
    char* Vd = (char*)Vs[bufi] + w * 2048;
    gload_lds16(q + ksrc + (size_t)(kt * 64) * 1024, Kd);
    gload_lds16(q + ksrc + (size_t)(kt * 64 + 8) * 1024, Kd + 1024);
    gload_lds16(qT + vsrc + kt * 64, Vd);
    gload_lds16(qT + vsrc + (size_t)8 * 1024 + kt * 64, Vd + 1024);
  };

  const int* mrow = mask + b * 1024;
  // --- one-time: is the whole mask row all-ones? (uniform fast path) ---
  if (tid == 0) allmask = 1;
  int mp = 1;
  #pragma unroll
  for (int i = 0; i < 4; ++i) mp &= (mrow[tid + i * 256] != 0);
  stage(0, 0);   // overlap staging with the mask scan
  __syncthreads();                 // allmask initialized; staging issued
  if (!__all(mp) && lane == 0) atomicAnd(&allmask, 0);
  asm volatile("s_waitcnt vmcnt(0)" ::: "memory");
  __syncthreads();
  const bool fullmask = (allmask != 0);

  short8 qa[2][2];
  #pragma unroll
  for (int qf = 0; qf < 2; ++qf)
    #pragma unroll
    for (int kk = 0; kk < 2; ++kk)
      qa[qf][kk] = *(const short8*)&q[qbase + (size_t)(q0 + qf * 16 + lq) * 1024 + kk * 32 + lk8];

  short8 ones;
  #pragma unroll
  for (int i = 0; i < 8; ++i) ones[i] = (short)0x3F80;  // bf16 1.0

  f32x4 lacc[2] = {};
  f32x4 Oa[2][4];
  #pragma unroll
  for (int mf = 0; mf < 2; ++mf)
    #pragma unroll
    for (int nf = 0; nf < 4; ++nf) Oa[mf][nf] = (f32x4){0.f, 0.f, 0.f, 0.f};

  int cur = 0;

  for (int kt = 0; kt < 16; ++kt) {
    const int k0 = kt * 64;
    if (kt < 15) stage(cur ^ 1, kt + 1);
    const char* Kb = (const char*)Ks[cur];
    const char* Vb = (const char*)Vs[cur];
    // --- St = K Q^T (already log2-domain) ---
    f32x4 s[2][4];
    #pragma unroll
    for (int qf = 0; qf < 2; ++qf)
      #pragma unroll
      for (int kf = 0; kf < 4; ++kf) s[qf][kf] = (f32x4){0.f, 0.f, 0.f, 0.f};
    #pragma unroll
    for (int kf = 0; kf < 4; ++kf) {
      const char* kr = Kb + (kf * 16 + lq) * 128;
      const short8 ka0 = *(const short8*)(kr + (((g) ^ swz) << 4));
      const short8 ka1 = *(const short8*)(kr + (((4 + g) ^ swz) << 4));
      s[0][kf] = MFMA16(ka0, qa[0][0], s[0][kf]);
      s[0][kf] = MFMA16(ka1, qa[0][1], s[0][kf]);
      s[1][kf] = MFMA16(ka0, qa[1][0], s[1][kf]);
      s[1][kf] = MFMA16(ka1, qa[1][1], s[1][kf]);
    }
    // --- mask add (skipped when all-ones; exp2(-1e9)=0 keeps masked cols 0) --
    if (!fullmask) {
      #pragma unroll
      for (int kf = 0; kf < 4; ++kf) {
        const int4 mv = *(const int4*)&mrow[k0 + kf * 16 + g * 4];
        float madd[4];
        madd[0] = mv.x ? 0.f : -1e9f; madd[1] = mv.y ? 0.f : -1e9f;
        madd[2] = mv.z ? 0.f : -1e9f; madd[3] = mv.w ? 0.f : -1e9f;
        #pragma unroll
        for (int qf = 0; qf < 2; ++qf)
          #pragma unroll
          for (int r = 0; r < 4; ++r)
            s[qf][kf][r] += madd[r];
      }
    }
    // --- P = exp2(s) (no max tracking), pack fully in registers ---
    unsigned int E[2][4], O[2][4];
    #pragma unroll
    for (int qf = 0; qf < 2; ++qf) {
      #pragma unroll
      for (int kf = 0; kf < 4; ++kf) {
        float p0 = exp2f(s[qf][kf][0]);
        float p1 = exp2f(s[qf][kf][1]);
        float p2 = exp2f(s[qf][kf][2]);
        float p3 = exp2f(s[qf][kf][3]);
        asm("v_cvt_pk_bf16_f32 %0, %1, %2" : "=v"(E[qf][kf]) : "v"(p0), "v"(p1));
        asm("v_cvt_pk_bf16_f32 %0, %1, %2" : "=v"(O[qf][kf]) : "v"(p2), "v"(p3));
      }
    }
    // --- rearrange P to PV A-frags: permlane32_swap + permlane16_swap ---
    short8 pa[2][2];
    #pragma unroll
    for (int qf = 0; qf < 2; ++qf) {
      #pragma unroll
      for (int ks = 0; ks < 2; ++ks) {
        unsigned int e0 = E[qf][2 * ks], e1 = E[qf][2 * ks + 1];
        unsigned int o0 = O[qf][2 * ks], o1 = O[qf][2 * ks + 1];
        asm("v_permlane32_swap_b32 %0, %1" : "+v"(e0), "+v"(e1));
        asm("v_permlane16_swap_b32 %0, %1" : "+v"(e0), "+v"(e1));
        asm("v_permlane32_swap_b32 %0, %1" : "+v"(o0), "+v"(o1));
        asm("v_permlane16_swap_b32 %0, %1" : "+v"(o0), "+v"(o1));
        union { unsigned int u[4]; short8 s8; } pw;
        pw.u[0] = e0; pw.u[1] = o0; pw.u[2] = e1; pw.u[3] = o1;
        pa[qf][ks] = pw.s8;
      }
    }
    // --- O += P @ V, l += P @ ones (row-sum on the matrix pipe) ---
    #pragma unroll
    for (int ks = 0; ks < 2; ++ks) {
      #pragma unroll
      for (int nf = 0; nf < 4; ++nf) {
        const short8 vb = *(const short8*)(Vb + (nf * 16 + lq) * 128 + (((4 * ks + g) ^ swz) << 4));
        Oa[0][nf] = MFMA16(pa[0][ks], vb, Oa[0][nf]);
        Oa[1][nf] = MFMA16(pa[1][ks], vb, Oa[1][nf]);
      }
      lacc[0] = MFMA16(pa[0][ks], ones, lacc[0]);
      lacc[1] = MFMA16(pa[1][ks], ones, lacc[1]);
    }
    __syncthreads();
    cur ^= 1;
  }
  // --- epilogue: l is per-row in lacc regs (all lanes identical) ---
  #pragma unroll
  for (int mf = 0; mf < 2; ++mf) {
    #pragma unroll
    for (int r = 0; r < 4; ++r) {
      const float linv = RS / lacc[mf][r];
      const int row = q0 + mf * 16 + g * 4 + r;
      #pragma unroll
      for (int nf = 0; nf < 4; ++nf) {
        const int col = h * 64 + nf * 16 + lq;
        ctx[((size_t)b * 1024 + row) * 1024 + col] = f2bf(Oa[mf][nf][r] * linv);
      }
    }
  }
}

// ---------------- launch ----------------------------------------------------
extern "C" void kernel_launch(void* const* d_in, const int* in_sizes, int n_in,
                              void* d_out, int out_size, void* d_ws, size_t ws_size,
                              hipStream_t stream) {
  const float* x    = (const float*)d_in[0];
  const int*   mask = (const int*)d_in[1];
  const float* wq   = (const float*)d_in[2];
  const float* bq   = (const float*)d_in[3];
  const float* wo   = (const float*)d_in[8];
  const float* bo   = (const float*)d_in[9];
  const float* w1   = (const float*)d_in[10];
  const float* b1   = (const float*)d_in[11];
  const float* w2   = (const float*)d_in[12];
  const float* b2   = (const float*)d_in[13];
  const float* ln1a = (const float*)d_in[14];
  const float* ln1b = (const float*)d_in[15];
  const float* ln2a = (const float*)d_in[16];
  const float* ln2b = (const float*)d_in[17];
  float* out = (float*)d_out;

  char* ws = (char*)d_ws;
  unsigned short* wq_b  = (unsigned short*)(ws);                  //  2 MB
  unsigned short* wo_b  = (unsigned short*)(ws + (2l << 20));     //  2 MB
  unsigned short* w1_b  = (unsigned short*)(ws + (4l << 20));     //  8 MB
  unsigned short* w2_b  = (unsigned short*)(ws + (12l << 20));    //  8 MB
  unsigned short* n_b   = (unsigned short*)(ws + (20l << 20));    // 16 MB (n, then n2)
  unsigned short* q_b   = (unsigned short*)(ws + (36l << 20));    // 16 MB
  unsigned short* qT_b  = (unsigned short*)(ws + (52l << 20));    // 16 MB
  unsigned short* ctx_b = (unsigned short*)(ws + (68l << 20));    // 16 MB
  unsigned short* h_b   = (unsigned short*)(ws + (84l << 20));    // 64 MB

  const float SQRT_SC = 0.42466090f;  // sqrt(0.125 * log2(e))

  CvtArgs ca{wq, wo, w1, w2, wq_b, wo_b, w1_b, w2_b};
  cvt_weights<<<10240, 256, 0, stream>>>(ca);
  ln_kernel<<<8192, 256, 0, stream>>>(x, ln1a, ln1b, n_b);
  // Q-proj: 256x128 tiles, grid 256, scaled, fused qT transpose
  gemm2ph<1, 0, 2, 1, 1><<<256, 512, 0, stream>>>(n_b, 1024, wq_b, 1024, bq, nullptr, q_b, qT_b, 8192, 1024, 1024, SQRT_SC, 8);
  attn_kernel<<<1024, 256, 0, stream>>>(q_b, qT_b, mask, ctx_b);
  // O-proj + residual(x): fp32 out, LDS-staged epilogue
  gemm2ph<0, 0, 2, 0, 1><<<256, 512, 0, stream>>>(ctx_b, 1024, wo_b, 1024, bo, x, out, nullptr, 8192, 1024, 1024, 1.0f, 8);
  ln_kernel<<<8192, 256, 0, stream>>>(out, ln2a, ln2b, n_b);
  // FFN1: 256x256 tile, grid 512, SINGLE-buffered (66.6KB LDS -> 2 blocks/CU)
  gemm2ph<1, 1, 4, 0, 0><<<512, 512, 0, stream>>>(n_b, 1024, w1_b, 1024, b1, nullptr, h_b, nullptr, 8192, 4096, 1024, 1.0f, 16);
  // FFN2: 256x128 tile, grid 256, double-buffered
  gemm2ph<0, 0, 2, 0, 1><<<256, 512, 0, stream>>>(h_b, 4096, w2_b, 4096, b2, out, out, nullptr, 8192, 1024, 4096, 1.0f, 8);
}

// Round 17
// 296.823 us; speedup vs baseline: 1.0537x; 1.0537x over previous
//
#include <hip/hip_runtime.h>
#include <hip/hip_bf16.h>

typedef __attribute__((ext_vector_type(8))) short short8;
typedef __attribute__((ext_vector_type(4))) float f32x4;

#define MFMA16(a, b, c) __builtin_amdgcn_mfma_f32_16x16x32_bf16((a), (b), (c), 0, 0, 0)

__device__ __forceinline__ unsigned short f2bf(float f) {
  union { float f; unsigned int u; } v; v.f = f;
  return (unsigned short)((v.u + 0x7fffu + ((v.u >> 16) & 1u)) >> 16);
}

__device__ __forceinline__ void gload_lds16(const void* g, void* l) {
  __builtin_amdgcn_global_load_lds((__attribute__((address_space(1))) void*)g,
                                   (__attribute__((address_space(3))) void*)l,
                                   16, 0, 0);
}

// ---------------- weight fp32 -> bf16 conversion (4 arrays in one launch) ----
struct CvtArgs {
  const float* s0; const float* s1; const float* s2; const float* s3;
  unsigned short* d0; unsigned short* d1; unsigned short* d2; unsigned short* d3;
};

__global__ __launch_bounds__(256) void cvt_weights(CvtArgs a) {
  const long N0 = 1048576, N1 = 1048576, N2 = 4194304;  // wq, wo, w1 (w2 rest)
  long i = ((long)blockIdx.x * 256 + threadIdx.x) * 4;
  const float* s; unsigned short* d; long off;
  if (i < N0)                { s = a.s0; d = a.d0; off = i; }
  else if (i < N0 + N1)      { s = a.s1; d = a.d1; off = i - N0; }
  else if (i < N0 + N1 + N2) { s = a.s2; d = a.d2; off = i - N0 - N1; }
  else                       { s = a.s3; d = a.d3; off = i - N0 - N1 - N2; }
  float4 v = *(const float4*)(s + off);
  ushort4 o;
  o.x = f2bf(v.x); o.y = f2bf(v.y); o.z = f2bf(v.z); o.w = f2bf(v.w);
  *(ushort4*)(d + off) = o;
}

// ---------------- LayerNorm (ddof=1, eps added to std), fp32 in -> bf16 out --
__global__ __launch_bounds__(256) void ln_kernel(
    const float* __restrict__ x,
    const float* __restrict__ alpha, const float* __restrict__ beta,
    unsigned short* __restrict__ out) {
  const int row = blockIdx.x;
  const int tid = threadIdx.x;
  const float4 v = ((const float4*)(x + (size_t)row * 1024))[tid];
  float s  = v.x + v.y + v.z + v.w;
  float sq = v.x * v.x + v.y * v.y + v.z * v.z + v.w * v.w;
  #pragma unroll
  for (int d = 32; d >= 1; d >>= 1) {
    s  += __shfl_xor(s, d, 64);
    sq += __shfl_xor(sq, d, 64);
  }
  __shared__ float red[8];
  const int w = tid >> 6;
  if ((tid & 63) == 0) { red[w] = s; red[4 + w] = sq; }
  __syncthreads();
  s  = red[0] + red[1] + red[2] + red[3];
  sq = red[4] + red[5] + red[6] + red[7];
  const float mean = s * (1.f / 1024.f);
  float var = (sq - s * mean) * (1.f / 1023.f);
  var = fmaxf(var, 0.f);
  const float rs = alpha[0] / (sqrtf(var) + 1e-6f);
  const float bb = beta[0];
  ushort4 o;
  o.x = f2bf((v.x - mean) * rs + bb);
  o.y = f2bf((v.y - mean) * rs + bb);
  o.z = f2bf((v.z - mean) * rs + bb);
  o.w = f2bf((v.w - mean) * rs + bb);
  ((ushort4*)out)[(size_t)row * 256 + tid] = o;
}

// ---------------- 2-phase 256xBN GEMM, C = A @ B^T + bias -------------------
// Double-buffered staging (DBUF=1, the proven config).
// bf16 out: LDS-staged coalesced epilogue (+optional fused qT transpose).
// fp32 out: LDS-staged coalesced epilogue with fused residual add.
template <int OUT_BF16, int RELU, int NF, int WQT, int DBUF>
__global__ __launch_bounds__(512, 2) void gemm2ph(
    const unsigned short* __restrict__ A, int lda,
    const unsigned short* __restrict__ B, int ldb,
    const float* __restrict__ bias,
    const float* __restrict__ residual,
    void* __restrict__ Cout,
    unsigned short* __restrict__ qTout,
    int M, int N, int K, float cscale, int nbx) {
  constexpr int STG = DBUF ? (32768 + NF * 8192) : (16384 + NF * 4096);
  constexpr int EPI = OUT_BF16 ? 128 * (NF * 64 + 4) : 256 * (NF * 64 + 4);
  constexpr int LSH = STG > EPI ? STG : EPI;
  __shared__ __align__(16) unsigned short lds[LSH];
  const int NT = K >> 6;
  const int tid = threadIdx.x;
  const int w = tid >> 6, lane = tid & 63;
  const int cpx = gridDim.x >> 3;
  const int id = (blockIdx.x & 7) * cpx + (blockIdx.x >> 3);  // XCD swizzle
  const int bx = id % nbx, by = id / nbx;
  const int row0 = by * 256, col0 = bx * (NF * 64);
  const int wr128 = (w >> 2) * 128, wcN = (w & 3) * (NF * 16);
  const int lq = lane & 15, g = lane >> 4, g4 = g * 4;
  const int strow = tid >> 3;                        // 0..63
  const int sunit8 = ((tid & 7) ^ (strow & 7)) * 8;  // inverse-swizzled k-off

  const unsigned short* Asrc = A + (size_t)(row0 + strow) * lda + sunit8;
  const unsigned short* Bsrc = B + (size_t)(col0 + strow) * ldb + sunit8;

  auto stage = [&](int buf, int tt) {
    unsigned short* Ad = lds + (DBUF ? buf * 16384 : 0) + w * 512;
    unsigned short* Bd = lds + (DBUF ? 32768 + buf * (NF * 4096) : 16384) + w * 512;
    #pragma unroll
    for (int c = 0; c < 4; ++c)
      gload_lds16(Asrc + (size_t)(c * 64) * lda + tt * 64, Ad + c * 4096);
    #pragma unroll
    for (int c = 0; c < NF; ++c)
      gload_lds16(Bsrc + (size_t)(c * 64) * ldb + tt * 64, Bd + c * 4096);
  };

  f32x4 acc[8][NF] = {};

  auto compute = [&](int buf) {
    const unsigned short* Ab = lds + (DBUF ? buf * 16384 : 0);
    const unsigned short* Bb = lds + (DBUF ? 32768 + buf * (NF * 4096) : 16384);
    #pragma unroll
    for (int kk = 0; kk < 2; ++kk) {
      short8 af[8], bf[NF];
      #pragma unroll
      for (int m = 0; m < 8; ++m) {
        const int r = wr128 + m * 16 + lq;
        af[m] = *(const short8*)(Ab + r * 64 + (((kk * 4 + g) ^ (r & 7)) << 3));
      }
      #pragma unroll
      for (int n = 0; n < NF; ++n) {
        const int r = wcN + n * 16 + lq;
        bf[n] = *(const short8*)(Bb + r * 64 + (((kk * 4 + g) ^ (r & 7)) << 3));
      }
      __builtin_amdgcn_s_setprio(1);
      #pragma unroll
      for (int m = 0; m < 8; ++m)
        #pragma unroll
        for (int n = 0; n < NF; ++n)
          acc[m][n] = MFMA16(af[m], bf[n], acc[m][n]);
      __builtin_amdgcn_s_setprio(0);
    }
  };

  if (DBUF) {
    stage(0, 0);
    asm volatile("s_waitcnt vmcnt(0)" ::: "memory");
    __builtin_amdgcn_s_barrier();
    int buf = 0;
    for (int t = 0; t < NT; ++t) {
      if (t + 1 < NT) stage(buf ^ 1, t + 1);
      compute(buf);
      if (t + 1 < NT) {
        asm volatile("s_waitcnt vmcnt(0)" ::: "memory");
        __builtin_amdgcn_s_barrier();
        buf ^= 1;
      }
    }
  } else {
    for (int t = 0; t < NT; ++t) {
      __syncthreads();
      stage(0, t);
      asm volatile("s_waitcnt vmcnt(0)" ::: "memory");
      __syncthreads();
      compute(0);
    }
  }

  // ---- epilogue ----
  float bv[NF];
  #pragma unroll
  for (int n = 0; n < NF; ++n) bv[n] = bias[col0 + wcN + n * 16 + lq];

  if (OUT_BF16) {
    // stage C tile through LDS (padded stride), coalesced row copies
    const int CW = NF * 64 + 4;
    unsigned short* cbuf = lds;
    __syncthreads();
    #pragma unroll
    for (int p = 0; p < 2; ++p) {
      if ((w >> 2) == p) {
        #pragma unroll
        for (int m = 0; m < 8; ++m)
          #pragma unroll
          for (int n = 0; n < NF; ++n)
            #pragma unroll
            for (int r = 0; r < 4; ++r) {
              float v = (acc[m][n][r] + bv[n]) * cscale;
              if (RELU) v = fmaxf(v, 0.f);
              cbuf[(m * 16 + g4 + r) * CW + wcN + n * 16 + lq] = f2bf(v);
            }
      }
      __syncthreads();
      #pragma unroll
      for (int i = 0; i < 2 * NF; ++i) {
        const int un = i * 512 + tid;
        const int row = un / (8 * NF);
        const int cu = un % (8 * NF);
        const short8 vv = *(const short8*)&cbuf[row * CW + cu * 8];
        *(short8*)((unsigned short*)Cout + (size_t)(row0 + p * 128 + row) * N + col0 + cu * 8) = vv;
      }
      if (WQT) {
        // fused transpose: qT[bh][d][s], 128 cols x 128 s from this half-tile
        const int grow = row0 + p * 128;
        const int bb = grow >> 10;
        const int s0 = grow & 1023;
        const int h0 = col0 >> 6;
        #pragma unroll
        for (int i = 0; i < 4; ++i) {
          const int un = i * 512 + tid;        // 2048 = 128 cols x 16 s-units
          const int colx = un >> 4;
          const int su = un & 15;
          const int hh = h0 + (colx >> 6);
          const int dd = colx & 63;
          short8 o;
          #pragma unroll
          for (int j = 0; j < 8; ++j) o[j] = (short)cbuf[(su * 8 + j) * CW + colx];
          *(short8*)(qTout + ((size_t)(bb * 16 + hh) * 64 + dd) * 1024 + s0 + su * 8) = o;
        }
      }
      __syncthreads();
    }
  } else {
    // fp32: stage half-tile in LDS, coalesced float4 rows + fused residual
    const int CWf = NF * 64 + 4;
    float* cbuf = (float*)lds;
    __syncthreads();
    #pragma unroll
    for (int p = 0; p < 2; ++p) {
      if ((w >> 2) == p) {
        #pragma unroll
        for (int m = 0; m < 8; ++m)
          #pragma unroll
          for (int n = 0; n < NF; ++n)
            #pragma unroll
            for (int r = 0; r < 4; ++r) {
              float v = (acc[m][n][r] + bv[n]) * cscale;
              if (RELU) v = fmaxf(v, 0.f);
              cbuf[(m * 16 + g4 + r) * CWf + wcN + n * 16 + lq] = v;
            }
      }
      __syncthreads();
      #pragma unroll
      for (int i = 0; i < 4 * NF; ++i) {
        const int un = i * 512 + tid;            // rows x (NF*16) float4 units
        const int row = un / (16 * NF);
        const int cu = un % (16 * NF);
        float4 v = *(const float4*)&cbuf[row * CWf + cu * 4];
        const size_t idx = (size_t)(row0 + p * 128 + row) * N + col0 + cu * 4;
        if (residual) {
          const float4 rv = *(const float4*)(residual + idx);
          v.x += rv.x; v.y += rv.y; v.z += rv.z; v.w += rv.w;
        }
        *(float4*)((float*)Cout + idx) = v;
      }
      __syncthreads();
    }
  }
}

// ---------------- flash attention v9: no-max softmax (bounded domain) --------
__global__ __launch_bounds__(256) void attn_kernel(
    const unsigned short* __restrict__ q,    // [B,S,1024] bf16 (scaled)
    const unsigned short* __restrict__ qT,   // [B*H,64,1024] bf16 (scaled)
    const int* __restrict__ mask,            // [B,1024]
    unsigned short* __restrict__ ctx) {      // [B,S,1024] bf16
  __shared__ __align__(16) unsigned short Ks[2][64 * 64];
  __shared__ __align__(16) unsigned short Vs[2][64 * 64];
  __shared__ int allmask;
  const int id = blockIdx.x;
  const int bh = ((id & 7) << 4) + (id >> 6);      // same-XCD blocks share bh set
  const int qt = (id >> 3) & 7;
  const int b = bh >> 4, h = bh & 15;
  const int tid = threadIdx.x, w = tid >> 6, lane = tid & 63;
  const int lq = lane & 15;
  const int g = lane >> 4;
  const int lk8 = g * 8;
  const int swz = lane & 7;
  const int q0 = qt * 128 + w * 32;
  const size_t qbase = (size_t)b * (1024 * 1024) + h * 64;
  const size_t qTb = (size_t)bh * 64 * 1024;
  const int srow = lane >> 3;                      // 0..7
  const int su = (lane & 7) ^ srow;                // inverse-swizzled unit
  const size_t ksrc = qbase + (size_t)(w * 16 + srow) * 1024 + su * 8;
  const size_t vsrc = qTb + (size_t)(w * 16 + srow) * 1024 + su * 8;
  const float RS = 2.3548202f;                     // 1/sqrt(0.125*log2e)

  auto stage = [&](int bufi, int kt) {
    char* Kd = (char*)Ks[bufi] + w * 2048;
    char* Vd = (char*)Vs[bufi] + w * 2048;
    gload_lds16(q + ksrc + (size_t)(kt * 64) * 1024, Kd);
    gload_lds16(q + ksrc + (size_t)(kt * 64 + 8) * 1024, Kd + 1024);
    gload_lds16(qT + vsrc + kt * 64, Vd);
    gload_lds16(qT + vsrc + (size_t)8 * 1024 + kt * 64, Vd + 1024);
  };

  const int* mrow = mask + b * 1024;
  // --- one-time: is the whole mask row all-ones? (uniform fast path) ---
  if (tid == 0) allmask = 1;
  int mp = 1;
  #pragma unroll
  for (int i = 0; i < 4; ++i) mp &= (mrow[tid + i * 256] != 0);
  stage(0, 0);   // overlap staging with the mask scan
  __syncthreads();                 // allmask initialized; staging issued
  if (!__all(mp) && lane == 0) atomicAnd(&allmask, 0);
  asm volatile("s_waitcnt vmcnt(0)" ::: "memory");
  __syncthreads();
  const bool fullmask = (allmask != 0);

  short8 qa[2][2];
  #pragma unroll
  for (int qf = 0; qf < 2; ++qf)
    #pragma unroll
    for (int kk = 0; kk < 2; ++kk)
      qa[qf][kk] = *(const short8*)&q[qbase + (size_t)(q0 + qf * 16 + lq) * 1024 + kk * 32 + lk8];

  short8 ones;
  #pragma unroll
  for (int i = 0; i < 8; ++i) ones[i] = (short)0x3F80;  // bf16 1.0

  f32x4 lacc[2] = {};
  f32x4 Oa[2][4];
  #pragma unroll
  for (int mf = 0; mf < 2; ++mf)
    #pragma unroll
    for (int nf = 0; nf < 4; ++nf) Oa[mf][nf] = (f32x4){0.f, 0.f, 0.f, 0.f};

  int cur = 0;

  for (int kt = 0; kt < 16; ++kt) {
    const int k0 = kt * 64;
    if (kt < 15) stage(cur ^ 1, kt + 1);
    const char* Kb = (const char*)Ks[cur];
    const char* Vb = (const char*)Vs[cur];
    // --- St = K Q^T (already log2-domain) ---
    f32x4 s[2][4];
    #pragma unroll
    for (int qf = 0; qf < 2; ++qf)
      #pragma unroll
      for (int kf = 0; kf < 4; ++kf) s[qf][kf] = (f32x4){0.f, 0.f, 0.f, 0.f};
    #pragma unroll
    for (int kf = 0; kf < 4; ++kf) {
      const char* kr = Kb + (kf * 16 + lq) * 128;
      const short8 ka0 = *(const short8*)(kr + (((g) ^ swz) << 4));
      const short8 ka1 = *(const short8*)(kr + (((4 + g) ^ swz) << 4));
      s[0][kf] = MFMA16(ka0, qa[0][0], s[0][kf]);
      s[0][kf] = MFMA16(ka1, qa[0][1], s[0][kf]);
      s[1][kf] = MFMA16(ka0, qa[1][0], s[1][kf]);
      s[1][kf] = MFMA16(ka1, qa[1][1], s[1][kf]);
    }
    // --- mask add (skipped when all-ones; exp2(-1e9)=0 keeps masked cols 0) --
    if (!fullmask) {
      #pragma unroll
      for (int kf = 0; kf < 4; ++kf) {
        const int4 mv = *(const int4*)&mrow[k0 + kf * 16 + g * 4];
        float madd[4];
        madd[0] = mv.x ? 0.f : -1e9f; madd[1] = mv.y ? 0.f : -1e9f;
        madd[2] = mv.z ? 0.f : -1e9f; madd[3] = mv.w ? 0.f : -1e9f;
        #pragma unroll
        for (int qf = 0; qf < 2; ++qf)
          #pragma unroll
          for (int r = 0; r < 4; ++r)
            s[qf][kf][r] += madd[r];
      }
    }
    // --- P = exp2(s) (no max tracking), pack fully in registers ---
    unsigned int E[2][4], O[2][4];
    #pragma unroll
    for (int qf = 0; qf < 2; ++qf) {
      #pragma unroll
      for (int kf = 0; kf < 4; ++kf) {
        float p0 = exp2f(s[qf][kf][0]);
        float p1 = exp2f(s[qf][kf][1]);
        float p2 = exp2f(s[qf][kf][2]);
        float p3 = exp2f(s[qf][kf][3]);
        asm("v_cvt_pk_bf16_f32 %0, %1, %2" : "=v"(E[qf][kf]) : "v"(p0), "v"(p1));
        asm("v_cvt_pk_bf16_f32 %0, %1, %2" : "=v"(O[qf][kf]) : "v"(p2), "v"(p3));
      }
    }
    // --- rearrange P to PV A-frags: permlane32_swap + permlane16_swap ---
    short8 pa[2][2];
    #pragma unroll
    for (int qf = 0; qf < 2; ++qf) {
      #pragma unroll
      for (int ks = 0; ks < 2; ++ks) {
        unsigned int e0 = E[qf][2 * ks], e1 = E[qf][2 * ks + 1];
        unsigned int o0 = O[qf][2 * ks], o1 = O[qf][2 * ks + 1];
        asm("v_permlane32_swap_b32 %0, %1" : "+v"(e0), "+v"(e1));
        asm("v_permlane16_swap_b32 %0, %1" : "+v"(e0), "+v"(e1));
        asm("v_permlane32_swap_b32 %0, %1" : "+v"(o0), "+v"(o1));
        asm("v_permlane16_swap_b32 %0, %1" : "+v"(o0), "+v"(o1));
        union { unsigned int u[4]; short8 s8; } pw;
        pw.u[0] = e0; pw.u[1] = o0; pw.u[2] = e1; pw.u[3] = o1;
        pa[qf][ks] = pw.s8;
      }
    }
    // --- O += P @ V, l += P @ ones (row-sum on the matrix pipe) ---
    #pragma unroll
    for (int ks = 0; ks < 2; ++ks) {
      #pragma unroll
      for (int nf = 0; nf < 4; ++nf) {
        const short8 vb = *(const short8*)(Vb + (nf * 16 + lq) * 128 + (((4 * ks + g) ^ swz) << 4));
        Oa[0][nf] = MFMA16(pa[0][ks], vb, Oa[0][nf]);
        Oa[1][nf] = MFMA16(pa[1][ks], vb, Oa[1][nf]);
      }
      lacc[0] = MFMA16(pa[0][ks], ones, lacc[0]);
      lacc[1] = MFMA16(pa[1][ks], ones, lacc[1]);
    }
    __syncthreads();
    cur ^= 1;
  }
  // --- epilogue: l is per-row in lacc regs (all lanes identical) ---
  #pragma unroll
  for (int mf = 0; mf < 2; ++mf) {
    #pragma unroll
    for (int r = 0; r < 4; ++r) {
      const float linv = RS / lacc[mf][r];
      const int row = q0 + mf * 16 + g * 4 + r;
      #pragma unroll
      for (int nf = 0; nf < 4; ++nf) {
        const int col = h * 64 + nf * 16 + lq;
        ctx[((size_t)b * 1024 + row) * 1024 + col] = f2bf(Oa[mf][nf][r] * linv);
      }
    }
  }
}

// ---------------- launch ----------------------------------------------------
extern "C" void kernel_launch(void* const* d_in, const int* in_sizes, int n_in,
                              void* d_out, int out_size, void* d_ws, size_t ws_size,
                              hipStream_t stream) {
  const float* x    = (const float*)d_in[0];
  const int*   mask = (const int*)d_in[1];
  const float* wq   = (const float*)d_in[2];
  const float* bq   = (const float*)d_in[3];
  const float* wo   = (const float*)d_in[8];
  const float* bo   = (const float*)d_in[9];
  const float* w1   = (const float*)d_in[10];
  const float* b1   = (const float*)d_in[11];
  const float* w2   = (const float*)d_in[12];
  const float* b2   = (const float*)d_in[13];
  const float* ln1a = (const float*)d_in[14];
  const float* ln1b = (const float*)d_in[15];
  const float* ln2a = (const float*)d_in[16];
  const float* ln2b = (const float*)d_in[17];
  float* out = (float*)d_out;

  char* ws = (char*)d_ws;
  unsigned short* wq_b  = (unsigned short*)(ws);                  //  2 MB
  unsigned short* wo_b  = (unsigned short*)(ws + (2l << 20));     //  2 MB
  unsigned short* w1_b  = (unsigned short*)(ws + (4l << 20));     //  8 MB
  unsigned short* w2_b  = (unsigned short*)(ws + (12l << 20));    //  8 MB
  unsigned short* n_b   = (unsigned short*)(ws + (20l << 20));    // 16 MB (n, then n2)
  unsigned short* q_b   = (unsigned short*)(ws + (36l << 20));    // 16 MB
  unsigned short* qT_b  = (unsigned short*)(ws + (52l << 20));    // 16 MB
  unsigned short* ctx_b = (unsigned short*)(ws + (68l << 20));    // 16 MB
  unsigned short* h_b   = (unsigned short*)(ws + (84l << 20));    // 64 MB

  const float SQRT_SC = 0.42466090f;  // sqrt(0.125 * log2(e))

  CvtArgs ca{wq, wo, w1, w2, wq_b, wo_b, w1_b, w2_b};
  cvt_weights<<<10240, 256, 0, stream>>>(ca);
  ln_kernel<<<8192, 256, 0, stream>>>(x, ln1a, ln1b, n_b);
  // Q-proj: 256x128 tiles, grid 256, scaled, fused qT transpose
  gemm2ph<1, 0, 2, 1, 1><<<256, 512, 0, stream>>>(n_b, 1024, wq_b, 1024, bq, nullptr, q_b, qT_b, 8192, 1024, 1024, SQRT_SC, 8);
  attn_kernel<<<1024, 256, 0, stream>>>(q_b, qT_b, mask, ctx_b);
  // O-proj + residual(x): fp32 out, LDS-staged epilogue
  gemm2ph<0, 0, 2, 0, 1><<<256, 512, 0, stream>>>(ctx_b, 1024, wo_b, 1024, bo, x, out, nullptr, 8192, 1024, 1024, 1.0f, 8);
  ln_kernel<<<8192, 256, 0, stream>>>(out, ln2a, ln2b, n_b);
  // FFN1: 256x256 tile, grid 512, double-buffered (proven champion config)
  gemm2ph<1, 1, 4, 0, 1><<<512, 512, 0, stream>>>(n_b, 1024, w1_b, 1024, b1, nullptr, h_b, nullptr, 8192, 4096, 1024, 1.0f, 16);
  // FFN2: 256x128 tile, grid 256, double-buffered
  gemm2ph<0, 0, 2, 0, 1><<<256, 512, 0, stream>>>(h_b, 4096, w2_b, 4096, b2, out, out, nullptr, 8192, 1024, 4096, 1.0f, 8);
}

// Round 18
// 278.551 us; speedup vs baseline: 1.1228x; 1.0656x over previous
//
#include <hip/hip_runtime.h>
#include <hip/hip_bf16.h>

typedef __attribute__((ext_vector_type(8))) short short8;
typedef __attribute__((ext_vector_type(4))) float f32x4;

#define MFMA16(a, b, c) __builtin_amdgcn_mfma_f32_16x16x32_bf16((a), (b), (c), 0, 0, 0)

__device__ __forceinline__ unsigned short f2bf(float f) {
  union { float f; unsigned int u; } v; v.f = f;
  return (unsigned short)((v.u + 0x7fffu + ((v.u >> 16) & 1u)) >> 16);
}

__device__ __forceinline__ void gload_lds16(const void* g, void* l) {
  __builtin_amdgcn_global_load_lds((__attribute__((address_space(1))) void*)g,
                                   (__attribute__((address_space(3))) void*)l,
                                   16, 0, 0);
}

// ---------------- fused: LN1 (blocks 0..8191) + weight cvt (rest) ------------
struct CvtArgs {
  const float* s0; const float* s1; const float* s2; const float* s3;
  unsigned short* d0; unsigned short* d1; unsigned short* d2; unsigned short* d3;
};

__global__ __launch_bounds__(256) void cvt_ln(
    CvtArgs a,
    const float* __restrict__ x,
    const float* __restrict__ alpha, const float* __restrict__ beta,
    unsigned short* __restrict__ out) {
  const int tid = threadIdx.x;
  if (blockIdx.x < 8192) {
    // ---- LayerNorm row (ddof=1, eps added to std), fp32 -> bf16 ----
    const int row = blockIdx.x;
    const float4 v = ((const float4*)(x + (size_t)row * 1024))[tid];
    float s  = v.x + v.y + v.z + v.w;
    float sq = v.x * v.x + v.y * v.y + v.z * v.z + v.w * v.w;
    #pragma unroll
    for (int d = 32; d >= 1; d >>= 1) {
      s  += __shfl_xor(s, d, 64);
      sq += __shfl_xor(sq, d, 64);
    }
    __shared__ float red[8];
    const int w = tid >> 6;
    if ((tid & 63) == 0) { red[w] = s; red[4 + w] = sq; }
    __syncthreads();
    s  = red[0] + red[1] + red[2] + red[3];
    sq = red[4] + red[5] + red[6] + red[7];
    const float mean = s * (1.f / 1024.f);
    float var = (sq - s * mean) * (1.f / 1023.f);
    var = fmaxf(var, 0.f);
    const float rs = alpha[0] / (sqrtf(var) + 1e-6f);
    const float bb = beta[0];
    ushort4 o;
    o.x = f2bf((v.x - mean) * rs + bb);
    o.y = f2bf((v.y - mean) * rs + bb);
    o.z = f2bf((v.z - mean) * rs + bb);
    o.w = f2bf((v.w - mean) * rs + bb);
    ((ushort4*)out)[(size_t)row * 256 + tid] = o;
  } else {
    // ---- weight fp32 -> bf16 ----
    const long N0 = 1048576, N1 = 1048576, N2 = 4194304;  // wq, wo, w1 (w2 rest)
    long i = ((long)(blockIdx.x - 8192) * 256 + tid) * 4;
    const float* s; unsigned short* d; long off;
    if (i < N0)                { s = a.s0; d = a.d0; off = i; }
    else if (i < N0 + N1)      { s = a.s1; d = a.d1; off = i - N0; }
    else if (i < N0 + N1 + N2) { s = a.s2; d = a.d2; off = i - N0 - N1; }
    else                       { s = a.s3; d = a.d3; off = i - N0 - N1 - N2; }
    float4 v = *(const float4*)(s + off);
    ushort4 o;
    o.x = f2bf(v.x); o.y = f2bf(v.y); o.z = f2bf(v.z); o.w = f2bf(v.w);
    *(ushort4*)(d + off) = o;
  }
}

// ---------------- LayerNorm (standalone, for ln2) ----------------------------
__global__ __launch_bounds__(256) void ln_kernel(
    const float* __restrict__ x,
    const float* __restrict__ alpha, const float* __restrict__ beta,
    unsigned short* __restrict__ out) {
  const int row = blockIdx.x;
  const int tid = threadIdx.x;
  const float4 v = ((const float4*)(x + (size_t)row * 1024))[tid];
  float s  = v.x + v.y + v.z + v.w;
  float sq = v.x * v.x + v.y * v.y + v.z * v.z + v.w * v.w;
  #pragma unroll
  for (int d = 32; d >= 1; d >>= 1) {
    s  += __shfl_xor(s, d, 64);
    sq += __shfl_xor(sq, d, 64);
  }
  __shared__ float red[8];
  const int w = tid >> 6;
  if ((tid & 63) == 0) { red[w] = s; red[4 + w] = sq; }
  __syncthreads();
  s  = red[0] + red[1] + red[2] + red[3];
  sq = red[4] + red[5] + red[6] + red[7];
  const float mean = s * (1.f / 1024.f);
  float var = (sq - s * mean) * (1.f / 1023.f);
  var = fmaxf(var, 0.f);
  const float rs = alpha[0] / (sqrtf(var) + 1e-6f);
  const float bb = beta[0];
  ushort4 o;
  o.x = f2bf((v.x - mean) * rs + bb);
  o.y = f2bf((v.y - mean) * rs + bb);
  o.z = f2bf((v.z - mean) * rs + bb);
  o.w = f2bf((v.w - mean) * rs + bb);
  ((ushort4*)out)[(size_t)row * 256 + tid] = o;
}

// ---------------- 2-phase 256xBN GEMM, C = A @ B^T + bias -------------------
// Double-buffered staging (DBUF=1, the proven config).
// bf16 out: LDS-staged coalesced epilogue (+optional fused qT transpose).
// fp32 out: LDS-staged coalesced epilogue with fused residual add.
template <int OUT_BF16, int RELU, int NF, int WQT, int DBUF>
__global__ __launch_bounds__(512, 2) void gemm2ph(
    const unsigned short* __restrict__ A, int lda,
    const unsigned short* __restrict__ B, int ldb,
    const float* __restrict__ bias,
    const float* __restrict__ residual,
    void* __restrict__ Cout,
    unsigned short* __restrict__ qTout,
    int M, int N, int K, float cscale, int nbx) {
  constexpr int STG = DBUF ? (32768 + NF * 8192) : (16384 + NF * 4096);
  constexpr int EPI = OUT_BF16 ? 128 * (NF * 64 + 4) : 256 * (NF * 64 + 4);
  constexpr int LSH = STG > EPI ? STG : EPI;
  __shared__ __align__(16) unsigned short lds[LSH];
  const int NT = K >> 6;
  const int tid = threadIdx.x;
  const int w = tid >> 6, lane = tid & 63;
  const int cpx = gridDim.x >> 3;
  const int id = (blockIdx.x & 7) * cpx + (blockIdx.x >> 3);  // XCD swizzle
  const int bx = id % nbx, by = id / nbx;
  const int row0 = by * 256, col0 = bx * (NF * 64);
  const int wr128 = (w >> 2) * 128, wcN = (w & 3) * (NF * 16);
  const int lq = lane & 15, g = lane >> 4, g4 = g * 4;
  const int strow = tid >> 3;                        // 0..63
  const int sunit8 = ((tid & 7) ^ (strow & 7)) * 8;  // inverse-swizzled k-off

  const unsigned short* Asrc = A + (size_t)(row0 + strow) * lda + sunit8;
  const unsigned short* Bsrc = B + (size_t)(col0 + strow) * ldb + sunit8;

  auto stage = [&](int buf, int tt) {
    unsigned short* Ad = lds + (DBUF ? buf * 16384 : 0) + w * 512;
    unsigned short* Bd = lds + (DBUF ? 32768 + buf * (NF * 4096) : 16384) + w * 512;
    #pragma unroll
    for (int c = 0; c < 4; ++c)
      gload_lds16(Asrc + (size_t)(c * 64) * lda + tt * 64, Ad + c * 4096);
    #pragma unroll
    for (int c = 0; c < NF; ++c)
      gload_lds16(Bsrc + (size_t)(c * 64) * ldb + tt * 64, Bd + c * 4096);
  };

  f32x4 acc[8][NF] = {};

  auto compute = [&](int buf) {
    const unsigned short* Ab = lds + (DBUF ? buf * 16384 : 0);
    const unsigned short* Bb = lds + (DBUF ? 32768 + buf * (NF * 4096) : 16384);
    #pragma unroll
    for (int kk = 0; kk < 2; ++kk) {
      short8 af[8], bf[NF];
      #pragma unroll
      for (int m = 0; m < 8; ++m) {
        const int r = wr128 + m * 16 + lq;
        af[m] = *(const short8*)(Ab + r * 64 + (((kk * 4 + g) ^ (r & 7)) << 3));
      }
      #pragma unroll
      for (int n = 0; n < NF; ++n) {
        const int r = wcN + n * 16 + lq;
        bf[n] = *(const short8*)(Bb + r * 64 + (((kk * 4 + g) ^ (r & 7)) << 3));
      }
      __builtin_amdgcn_s_setprio(1);
      #pragma unroll
      for (int m = 0; m < 8; ++m)
        #pragma unroll
        for (int n = 0; n < NF; ++n)
          acc[m][n] = MFMA16(af[m], bf[n], acc[m][n]);
      __builtin_amdgcn_s_setprio(0);
    }
  };

  if (DBUF) {
    stage(0, 0);
    asm volatile("s_waitcnt vmcnt(0)" ::: "memory");
    __builtin_amdgcn_s_barrier();
    int buf = 0;
    for (int t = 0; t < NT; ++t) {
      if (t + 1 < NT) stage(buf ^ 1, t + 1);
      compute(buf);
      if (t + 1 < NT) {
        asm volatile("s_waitcnt vmcnt(0)" ::: "memory");
        __builtin_amdgcn_s_barrier();
        buf ^= 1;
      }
    }
  } else {
    for (int t = 0; t < NT; ++t) {
      __syncthreads();
      stage(0, t);
      asm volatile("s_waitcnt vmcnt(0)" ::: "memory");
      __syncthreads();
      compute(0);
    }
  }

  // ---- epilogue ----
  float bv[NF];
  #pragma unroll
  for (int n = 0; n < NF; ++n) bv[n] = bias[col0 + wcN + n * 16 + lq];

  if (OUT_BF16) {
    // stage C tile through LDS (padded stride), coalesced row copies
    const int CW = NF * 64 + 4;
    unsigned short* cbuf = lds;
    __syncthreads();
    #pragma unroll
    for (int p = 0; p < 2; ++p) {
      if ((w >> 2) == p) {
        #pragma unroll
        for (int m = 0; m < 8; ++m)
          #pragma unroll
          for (int n = 0; n < NF; ++n)
            #pragma unroll
            for (int r = 0; r < 4; ++r) {
              float v = (acc[m][n][r] + bv[n]) * cscale;
              if (RELU) v = fmaxf(v, 0.f);
              cbuf[(m * 16 + g4 + r) * CW + wcN + n * 16 + lq] = f2bf(v);
            }
      }
      __syncthreads();
      #pragma unroll
      for (int i = 0; i < 2 * NF; ++i) {
        const int un = i * 512 + tid;
        const int row = un / (8 * NF);
        const int cu = un % (8 * NF);
        const short8 vv = *(const short8*)&cbuf[row * CW + cu * 8];
        *(short8*)((unsigned short*)Cout + (size_t)(row0 + p * 128 + row) * N + col0 + cu * 8) = vv;
      }
      if (WQT) {
        // fused transpose: qT[bh][d][s], 128 cols x 128 s from this half-tile
        const int grow = row0 + p * 128;
        const int bb = grow >> 10;
        const int s0 = grow & 1023;
        const int h0 = col0 >> 6;
        #pragma unroll
        for (int i = 0; i < 4; ++i) {
          const int un = i * 512 + tid;        // 2048 = 128 cols x 16 s-units
          const int colx = un >> 4;
          const int su = un & 15;
          const int hh = h0 + (colx >> 6);
          const int dd = colx & 63;
          short8 o;
          #pragma unroll
          for (int j = 0; j < 8; ++j) o[j] = (short)cbuf[(su * 8 + j) * CW + colx];
          *(short8*)(qTout + ((size_t)(bb * 16 + hh) * 64 + dd) * 1024 + s0 + su * 8) = o;
        }
      }
      __syncthreads();
    }
  } else {
    // fp32: stage half-tile in LDS, coalesced float4 rows + fused residual
    const int CWf = NF * 64 + 4;
    float* cbuf = (float*)lds;
    __syncthreads();
    #pragma unroll
    for (int p = 0; p < 2; ++p) {
      if ((w >> 2) == p) {
        #pragma unroll
        for (int m = 0; m < 8; ++m)
          #pragma unroll
          for (int n = 0; n < NF; ++n)
            #pragma unroll
            for (int r = 0; r < 4; ++r) {
              float v = (acc[m][n][r] + bv[n]) * cscale;
              if (RELU) v = fmaxf(v, 0.f);
              cbuf[(m * 16 + g4 + r) * CWf + wcN + n * 16 + lq] = v;
            }
      }
      __syncthreads();
      #pragma unroll
      for (int i = 0; i < 4 * NF; ++i) {
        const int un = i * 512 + tid;            // rows x (NF*16) float4 units
        const int row = un / (16 * NF);
        const int cu = un % (16 * NF);
        float4 v = *(const float4*)&cbuf[row * CWf + cu * 4];
        const size_t idx = (size_t)(row0 + p * 128 + row) * N + col0 + cu * 4;
        if (residual) {
          const float4 rv = *(const float4*)(residual + idx);
          v.x += rv.x; v.y += rv.y; v.z += rv.z; v.w += rv.w;
        }
        *(float4*)((float*)Cout + idx) = v;
      }
      __syncthreads();
    }
  }
}

// ---------------- flash attention v10: 8 waves / 256 q-rows per block --------
// Grid 512 (XCD-grouped per bh). K/V staged once per 256 q-rows (half the
// chip-wide staging traffic of the 4-wave version). No-max exp2 softmax,
// reg-P via cvt_pk+permlane, l via ones-MFMA.
__global__ __launch_bounds__(512) void attn_kernel(
    const unsigned short* __restrict__ q,    // [B,S,1024] bf16 (scaled)
    const unsigned short* __restrict__ qT,   // [B*H,64,1024] bf16 (scaled)
    const int* __restrict__ mask,            // [B,1024]
    unsigned short* __restrict__ ctx) {      // [B,S,1024] bf16
  __shared__ __align__(16) unsigned short Ks[2][64 * 64];
  __shared__ __align__(16) unsigned short Vs[2][64 * 64];
  __shared__ int allmask;
  const int id = blockIdx.x;
  const int bh = ((id & 7) << 4) + (id >> 5);      // same-bh blocks -> same XCD
  const int qt = (id >> 3) & 3;
  const int b = bh >> 4, h = bh & 15;
  const int tid = threadIdx.x, w = tid >> 6, lane = tid & 63;
  const int lq = lane & 15;
  const int g = lane >> 4;
  const int lk8 = g * 8;
  const int swz = lane & 7;
  const int q0 = qt * 256 + w * 32;
  const size_t qbase = (size_t)b * (1024 * 1024) + h * 64;
  const size_t qTb = (size_t)bh * 64 * 1024;
  const int srow = lane >> 3;                      // 0..7
  const int su = (lane & 7) ^ srow;                // inverse-swizzled unit
  // wave w stages rows [w*8, w*8+8) of K and of V (1 gload each)
  const size_t ksrc = qbase + (size_t)(w * 8 + srow) * 1024 + su * 8;
  const size_t vsrc = qTb + (size_t)(w * 8 + srow) * 1024 + su * 8;
  const float RS = 2.3548202f;                     // 1/sqrt(0.125*log2e)

  auto stage = [&](int bufi, int kt) {
    gload_lds16(q + ksrc + (size_t)(kt * 64) * 1024, (char*)Ks[bufi] + w * 1024);
    gload_lds16(qT + vsrc + kt * 64, (char*)Vs[bufi] + w * 1024);
  };

  const int* mrow = mask + b * 1024;
  // --- one-time: is the whole mask row all-ones? (uniform fast path) ---
  if (tid == 0) allmask = 1;
  int mp = 1;
  #pragma unroll
  for (int i = 0; i < 2; ++i) mp &= (mrow[tid + i * 512] != 0);
  stage(0, 0);   // overlap staging with the mask scan
  __syncthreads();                 // allmask initialized; staging issued
  if (!__all(mp) && lane == 0) atomicAnd(&allmask, 0);
  asm volatile("s_waitcnt vmcnt(0)" ::: "memory");
  __syncthreads();
  const bool fullmask = (allmask != 0);

  short8 qa[2][2];
  #pragma unroll
  for (int qf = 0; qf < 2; ++qf)
    #pragma unroll
    for (int kk = 0; kk < 2; ++kk)
      qa[qf][kk] = *(const short8*)&q[qbase + (size_t)(q0 + qf * 16 + lq) * 1024 + kk * 32 + lk8];

  short8 ones;
  #pragma unroll
  for (int i = 0; i < 8; ++i) ones[i] = (short)0x3F80;  // bf16 1.0

  f32x4 lacc[2] = {};
  f32x4 Oa[2][4];
  #pragma unroll
  for (int mf = 0; mf < 2; ++mf)
    #pragma unroll
    for (int nf = 0; nf < 4; ++nf) Oa[mf][nf] = (f32x4){0.f, 0.f, 0.f, 0.f};

  int cur = 0;

  for (int kt = 0; kt < 16; ++kt) {
    const int k0 = kt * 64;
    if (kt < 15) stage(cur ^ 1, kt + 1);
    const char* Kb = (const char*)Ks[cur];
    const char* Vb = (const char*)Vs[cur];
    // --- St = K Q^T (already log2-domain) ---
    f32x4 s[2][4];
    #pragma unroll
    for (int qf = 0; qf < 2; ++qf)
      #pragma unroll
      for (int kf = 0; kf < 4; ++kf) s[qf][kf] = (f32x4){0.f, 0.f, 0.f, 0.f};
    #pragma unroll
    for (int kf = 0; kf < 4; ++kf) {
      const char* kr = Kb + (kf * 16 + lq) * 128;
      const short8 ka0 = *(const short8*)(kr + (((g) ^ swz) << 4));
      const short8 ka1 = *(const short8*)(kr + (((4 + g) ^ swz) << 4));
      s[0][kf] = MFMA16(ka0, qa[0][0], s[0][kf]);
      s[0][kf] = MFMA16(ka1, qa[0][1], s[0][kf]);
      s[1][kf] = MFMA16(ka0, qa[1][0], s[1][kf]);
      s[1][kf] = MFMA16(ka1, qa[1][1], s[1][kf]);
    }
    // --- mask add (skipped when all-ones; exp2(-1e9)=0 keeps masked cols 0) --
    if (!fullmask) {
      #pragma unroll
      for (int kf = 0; kf < 4; ++kf) {
        const int4 mv = *(const int4*)&mrow[k0 + kf * 16 + g * 4];
        float madd[4];
        madd[0] = mv.x ? 0.f : -1e9f; madd[1] = mv.y ? 0.f : -1e9f;
        madd[2] = mv.z ? 0.f : -1e9f; madd[3] = mv.w ? 0.f : -1e9f;
        #pragma unroll
        for (int qf = 0; qf < 2; ++qf)
          #pragma unroll
          for (int r = 0; r < 4; ++r)
            s[qf][kf][r] += madd[r];
      }
    }
    // --- P = exp2(s) (no max tracking), pack fully in registers ---
    unsigned int E[2][4], O[2][4];
    #pragma unroll
    for (int qf = 0; qf < 2; ++qf) {
      #pragma unroll
      for (int kf = 0; kf < 4; ++kf) {
        float p0 = exp2f(s[qf][kf][0]);
        float p1 = exp2f(s[qf][kf][1]);
        float p2 = exp2f(s[qf][kf][2]);
        float p3 = exp2f(s[qf][kf][3]);
        asm("v_cvt_pk_bf16_f32 %0, %1, %2" : "=v"(E[qf][kf]) : "v"(p0), "v"(p1));
        asm("v_cvt_pk_bf16_f32 %0, %1, %2" : "=v"(O[qf][kf]) : "v"(p2), "v"(p3));
      }
    }
    // --- rearrange P to PV A-frags: permlane32_swap + permlane16_swap ---
    short8 pa[2][2];
    #pragma unroll
    for (int qf = 0; qf < 2; ++qf) {
      #pragma unroll
      for (int ks = 0; ks < 2; ++ks) {
        unsigned int e0 = E[qf][2 * ks], e1 = E[qf][2 * ks + 1];
        unsigned int o0 = O[qf][2 * ks], o1 = O[qf][2 * ks + 1];
        asm("v_permlane32_swap_b32 %0, %1" : "+v"(e0), "+v"(e1));
        asm("v_permlane16_swap_b32 %0, %1" : "+v"(e0), "+v"(e1));
        asm("v_permlane32_swap_b32 %0, %1" : "+v"(o0), "+v"(o1));
        asm("v_permlane16_swap_b32 %0, %1" : "+v"(o0), "+v"(o1));
        union { unsigned int u[4]; short8 s8; } pw;
        pw.u[0] = e0; pw.u[1] = o0; pw.u[2] = e1; pw.u[3] = o1;
        pa[qf][ks] = pw.s8;
      }
    }
    // --- O += P @ V, l += P @ ones (row-sum on the matrix pipe) ---
    #pragma unroll
    for (int ks = 0; ks < 2; ++ks) {
      #pragma unroll
      for (int nf = 0; nf < 4; ++nf) {
        const short8 vb = *(const short8*)(Vb + (nf * 16 + lq) * 128 + (((4 * ks + g) ^ swz) << 4));
        Oa[0][nf] = MFMA16(pa[0][ks], vb, Oa[0][nf]);
        Oa[1][nf] = MFMA16(pa[1][ks], vb, Oa[1][nf]);
      }
      lacc[0] = MFMA16(pa[0][ks], ones, lacc[0]);
      lacc[1] = MFMA16(pa[1][ks], ones, lacc[1]);
    }
    __syncthreads();
    cur ^= 1;
  }
  // --- epilogue: l is per-row in lacc regs (all lanes identical) ---
  #pragma unroll
  for (int mf = 0; mf < 2; ++mf) {
    #pragma unroll
    for (int r = 0; r < 4; ++r) {
      const float linv = RS / lacc[mf][r];
      const int row = q0 + mf * 16 + g * 4 + r;
      #pragma unroll
      for (int nf = 0; nf < 4; ++nf) {
        const int col = h * 64 + nf * 16 + lq;
        ctx[((size_t)b * 1024 + row) * 1024 + col] = f2bf(Oa[mf][nf][r] * linv);
      }
    }
  }
}

// ---------------- launch ----------------------------------------------------
extern "C" void kernel_launch(void* const* d_in, const int* in_sizes, int n_in,
                              void* d_out, int out_size, void* d_ws, size_t ws_size,
                              hipStream_t stream) {
  const float* x    = (const float*)d_in[0];
  const int*   mask = (const int*)d_in[1];
  const float* wq   = (const float*)d_in[2];
  const float* bq   = (const float*)d_in[3];
  const float* wo   = (const float*)d_in[8];
  const float* bo   = (const float*)d_in[9];
  const float* w1   = (const float*)d_in[10];
  const float* b1   = (const float*)d_in[11];
  const float* w2   = (const float*)d_in[12];
  const float* b2   = (const float*)d_in[13];
  const float* ln1a = (const float*)d_in[14];
  const float* ln1b = (const float*)d_in[15];
  const float* ln2a = (const float*)d_in[16];
  const float* ln2b = (const float*)d_in[17];
  float* out = (float*)d_out;

  char* ws = (char*)d_ws;
  unsigned short* wq_b  = (unsigned short*)(ws);                  //  2 MB
  unsigned short* wo_b  = (unsigned short*)(ws + (2l << 20));     //  2 MB
  unsigned short* w1_b  = (unsigned short*)(ws + (4l << 20));     //  8 MB
  unsigned short* w2_b  = (unsigned short*)(ws + (12l << 20));    //  8 MB
  unsigned short* n_b   = (unsigned short*)(ws + (20l << 20));    // 16 MB (n, then n2)
  unsigned short* q_b   = (unsigned short*)(ws + (36l << 20));    // 16 MB
  unsigned short* qT_b  = (unsigned short*)(ws + (52l << 20));    // 16 MB
  unsigned short* ctx_b = (unsigned short*)(ws + (68l << 20));    // 16 MB
  unsigned short* h_b   = (unsigned short*)(ws + (84l << 20));    // 64 MB

  const float SQRT_SC = 0.42466090f;  // sqrt(0.125 * log2(e))

  CvtArgs ca{wq, wo, w1, w2, wq_b, wo_b, w1_b, w2_b};
  // fused LN1 (8192 blocks) + weight cvt (10240 blocks)
  cvt_ln<<<18432, 256, 0, stream>>>(ca, x, ln1a, ln1b, n_b);
  // Q-proj: 256x128 tiles, grid 256, scaled, fused qT transpose
  gemm2ph<1, 0, 2, 1, 1><<<256, 512, 0, stream>>>(n_b, 1024, wq_b, 1024, bq, nullptr, q_b, qT_b, 8192, 1024, 1024, SQRT_SC, 8);
  attn_kernel<<<512, 512, 0, stream>>>(q_b, qT_b, mask, ctx_b);
  // O-proj + residual(x): fp32 out, LDS-staged epilogue
  gemm2ph<0, 0, 2, 0, 1><<<256, 512, 0, stream>>>(ctx_b, 1024, wo_b, 1024, bo, x, out, nullptr, 8192, 1024, 1024, 1.0f, 8);
  ln_kernel<<<8192, 256, 0, stream>>>(out, ln2a, ln2b, n_b);
  // FFN1: 256x256 tile, grid 512, double-buffered (champion config)
  gemm2ph<1, 1, 4, 0, 1><<<512, 512, 0, stream>>>(n_b, 1024, w1_b, 1024, b1, nullptr, h_b, nullptr, 8192, 4096, 1024, 1.0f, 16);
  // FFN2: 256x128 tile, grid 256, double-buffered
  gemm2ph<0, 0, 2, 0, 1><<<256, 512, 0, stream>>>(h_b, 4096, w2_b, 4096, b2, out, out, nullptr, 8192, 1024, 4096, 1.0f, 8);
}

// Round 19
// 277.133 us; speedup vs baseline: 1.1286x; 1.0051x over previous
//
#include <hip/hip_runtime.h>
#include <hip/hip_bf16.h>

typedef __attribute__((ext_vector_type(8))) short short8;
typedef __attribute__((ext_vector_type(4))) float f32x4;

#define MFMA16(a, b, c) __builtin_amdgcn_mfma_f32_16x16x32_bf16((a), (b), (c), 0, 0, 0)

__device__ __forceinline__ unsigned short f2bf(float f) {
  union { float f; unsigned int u; } v; v.f = f;
  return (unsigned short)((v.u + 0x7fffu + ((v.u >> 16) & 1u)) >> 16);
}

__device__ __forceinline__ void gload_lds16(const void* g, void* l) {
  __builtin_amdgcn_global_load_lds((__attribute__((address_space(1))) void*)g,
                                   (__attribute__((address_space(3))) void*)l,
                                   16, 0, 0);
}

// ---------------- fused: LN1 (blocks 0..8191) + weight cvt (rest) ------------
struct CvtArgs {
  const float* s0; const float* s1; const float* s2; const float* s3;
  unsigned short* d0; unsigned short* d1; unsigned short* d2; unsigned short* d3;
};

__global__ __launch_bounds__(256) void cvt_ln(
    CvtArgs a,
    const float* __restrict__ x,
    const float* __restrict__ alpha, const float* __restrict__ beta,
    unsigned short* __restrict__ out) {
  const int tid = threadIdx.x;
  if (blockIdx.x < 8192) {
    const int row = blockIdx.x;
    const float4 v = ((const float4*)(x + (size_t)row * 1024))[tid];
    float s  = v.x + v.y + v.z + v.w;
    float sq = v.x * v.x + v.y * v.y + v.z * v.z + v.w * v.w;
    #pragma unroll
    for (int d = 32; d >= 1; d >>= 1) {
      s  += __shfl_xor(s, d, 64);
      sq += __shfl_xor(sq, d, 64);
    }
    __shared__ float red[8];
    const int w = tid >> 6;
    if ((tid & 63) == 0) { red[w] = s; red[4 + w] = sq; }
    __syncthreads();
    s  = red[0] + red[1] + red[2] + red[3];
    sq = red[4] + red[5] + red[6] + red[7];
    const float mean = s * (1.f / 1024.f);
    float var = (sq - s * mean) * (1.f / 1023.f);
    var = fmaxf(var, 0.f);
    const float rs = alpha[0] / (sqrtf(var) + 1e-6f);
    const float bb = beta[0];
    ushort4 o;
    o.x = f2bf((v.x - mean) * rs + bb);
    o.y = f2bf((v.y - mean) * rs + bb);
    o.z = f2bf((v.z - mean) * rs + bb);
    o.w = f2bf((v.w - mean) * rs + bb);
    ((ushort4*)out)[(size_t)row * 256 + tid] = o;
  } else {
    const long N0 = 1048576, N1 = 1048576, N2 = 4194304;  // wq, wo, w1 (w2 rest)
    long i = ((long)(blockIdx.x - 8192) * 256 + tid) * 4;
    const float* s; unsigned short* d; long off;
    if (i < N0)                { s = a.s0; d = a.d0; off = i; }
    else if (i < N0 + N1)      { s = a.s1; d = a.d1; off = i - N0; }
    else if (i < N0 + N1 + N2) { s = a.s2; d = a.d2; off = i - N0 - N1; }
    else                       { s = a.s3; d = a.d3; off = i - N0 - N1 - N2; }
    float4 v = *(const float4*)(s + off);
    ushort4 o;
    o.x = f2bf(v.x); o.y = f2bf(v.y); o.z = f2bf(v.z); o.w = f2bf(v.w);
    *(ushort4*)(d + off) = o;
  }
}

// ---------------- LayerNorm (standalone, for ln2) ----------------------------
__global__ __launch_bounds__(256) void ln_kernel(
    const float* __restrict__ x,
    const float* __restrict__ alpha, const float* __restrict__ beta,
    unsigned short* __restrict__ out) {
  const int row = blockIdx.x;
  const int tid = threadIdx.x;
  const float4 v = ((const float4*)(x + (size_t)row * 1024))[tid];
  float s  = v.x + v.y + v.z + v.w;
  float sq = v.x * v.x + v.y * v.y + v.z * v.z + v.w * v.w;
  #pragma unroll
  for (int d = 32; d >= 1; d >>= 1) {
    s  += __shfl_xor(s, d, 64);
    sq += __shfl_xor(sq, d, 64);
  }
  __shared__ float red[8];
  const int w = tid >> 6;
  if ((tid & 63) == 0) { red[w] = s; red[4 + w] = sq; }
  __syncthreads();
  s  = red[0] + red[1] + red[2] + red[3];
  sq = red[4] + red[5] + red[6] + red[7];
  const float mean = s * (1.f / 1024.f);
  float var = (sq - s * mean) * (1.f / 1023.f);
  var = fmaxf(var, 0.f);
  const float rs = alpha[0] / (sqrtf(var) + 1e-6f);
  const float bb = beta[0];
  ushort4 o;
  o.x = f2bf((v.x - mean) * rs + bb);
  o.y = f2bf((v.y - mean) * rs + bb);
  o.z = f2bf((v.z - mean) * rs + bb);
  o.w = f2bf((v.w - mean) * rs + bb);
  ((ushort4*)out)[(size_t)row * 256 + tid] = o;
}

// ---------------- 2-phase 256xBN GEMM, C = A @ B^T + bias -------------------
template <int OUT_BF16, int RELU, int NF, int WQT, int DBUF>
__global__ __launch_bounds__(512, 2) void gemm2ph(
    const unsigned short* __restrict__ A, int lda,
    const unsigned short* __restrict__ B, int ldb,
    const float* __restrict__ bias,
    const float* __restrict__ residual,
    void* __restrict__ Cout,
    unsigned short* __restrict__ qTout,
    int M, int N, int K, float cscale, int nbx) {
  constexpr int STG = DBUF ? (32768 + NF * 8192) : (16384 + NF * 4096);
  constexpr int EPI = OUT_BF16 ? 128 * (NF * 64 + 4) : 256 * (NF * 64 + 4);
  constexpr int LSH = STG > EPI ? STG : EPI;
  __shared__ __align__(16) unsigned short lds[LSH];
  const int NT = K >> 6;
  const int tid = threadIdx.x;
  const int w = tid >> 6, lane = tid & 63;
  const int cpx = gridDim.x >> 3;
  const int id = (blockIdx.x & 7) * cpx + (blockIdx.x >> 3);  // XCD swizzle
  const int bx = id % nbx, by = id / nbx;
  const int row0 = by * 256, col0 = bx * (NF * 64);
  const int wr128 = (w >> 2) * 128, wcN = (w & 3) * (NF * 16);
  const int lq = lane & 15, g = lane >> 4, g4 = g * 4;
  const int strow = tid >> 3;                        // 0..63
  const int sunit8 = ((tid & 7) ^ (strow & 7)) * 8;  // inverse-swizzled k-off

  const unsigned short* Asrc = A + (size_t)(row0 + strow) * lda + sunit8;
  const unsigned short* Bsrc = B + (size_t)(col0 + strow) * ldb + sunit8;

  auto stage = [&](int buf, int tt) {
    unsigned short* Ad = lds + (DBUF ? buf * 16384 : 0) + w * 512;
    unsigned short* Bd = lds + (DBUF ? 32768 + buf * (NF * 4096) : 16384) + w * 512;
    #pragma unroll
    for (int c = 0; c < 4; ++c)
      gload_lds16(Asrc + (size_t)(c * 64) * lda + tt * 64, Ad + c * 4096);
    #pragma unroll
    for (int c = 0; c < NF; ++c)
      gload_lds16(Bsrc + (size_t)(c * 64) * ldb + tt * 64, Bd + c * 4096);
  };

  f32x4 acc[8][NF] = {};

  auto compute = [&](int buf) {
    const unsigned short* Ab = lds + (DBUF ? buf * 16384 : 0);
    const unsigned short* Bb = lds + (DBUF ? 32768 + buf * (NF * 4096) : 16384);
    #pragma unroll
    for (int kk = 0; kk < 2; ++kk) {
      short8 af[8], bf[NF];
      #pragma unroll
      for (int m = 0; m < 8; ++m) {
        const int r = wr128 + m * 16 + lq;
        af[m] = *(const short8*)(Ab + r * 64 + (((kk * 4 + g) ^ (r & 7)) << 3));
      }
      #pragma unroll
      for (int n = 0; n < NF; ++n) {
        const int r = wcN + n * 16 + lq;
        bf[n] = *(const short8*)(Bb + r * 64 + (((kk * 4 + g) ^ (r & 7)) << 3));
      }
      __builtin_amdgcn_s_setprio(1);
      #pragma unroll
      for (int m = 0; m < 8; ++m)
        #pragma unroll
        for (int n = 0; n < NF; ++n)
          acc[m][n] = MFMA16(af[m], bf[n], acc[m][n]);
      __builtin_amdgcn_s_setprio(0);
    }
  };

  if (DBUF) {
    stage(0, 0);
    asm volatile("s_waitcnt vmcnt(0)" ::: "memory");
    __builtin_amdgcn_s_barrier();
    int buf = 0;
    for (int t = 0; t < NT; ++t) {
      if (t + 1 < NT) stage(buf ^ 1, t + 1);
      compute(buf);
      if (t + 1 < NT) {
        asm volatile("s_waitcnt vmcnt(0)" ::: "memory");
        __builtin_amdgcn_s_barrier();
        buf ^= 1;
      }
    }
  } else {
    for (int t = 0; t < NT; ++t) {
      __syncthreads();
      stage(0, t);
      asm volatile("s_waitcnt vmcnt(0)" ::: "memory");
      __syncthreads();
      compute(0);
    }
  }

  // ---- epilogue ----
  float bv[NF];
  #pragma unroll
  for (int n = 0; n < NF; ++n) bv[n] = bias[col0 + wcN + n * 16 + lq];

  if (OUT_BF16) {
    const int CW = NF * 64 + 4;
    unsigned short* cbuf = lds;
    __syncthreads();
    #pragma unroll
    for (int p = 0; p < 2; ++p) {
      if ((w >> 2) == p) {
        #pragma unroll
        for (int m = 0; m < 8; ++m)
          #pragma unroll
          for (int n = 0; n < NF; ++n)
            #pragma unroll
            for (int r = 0; r < 4; ++r) {
              float v = (acc[m][n][r] + bv[n]) * cscale;
              if (RELU) v = fmaxf(v, 0.f);
              cbuf[(m * 16 + g4 + r) * CW + wcN + n * 16 + lq] = f2bf(v);
            }
      }
      __syncthreads();
      #pragma unroll
      for (int i = 0; i < 2 * NF; ++i) {
        const int un = i * 512 + tid;
        const int row = un / (8 * NF);
        const int cu = un % (8 * NF);
        const short8 vv = *(const short8*)&cbuf[row * CW + cu * 8];
        *(short8*)((unsigned short*)Cout + (size_t)(row0 + p * 128 + row) * N + col0 + cu * 8) = vv;
      }
      if (WQT) {
        const int grow = row0 + p * 128;
        const int bb = grow >> 10;
        const int s0 = grow & 1023;
        const int h0 = col0 >> 6;
        #pragma unroll
        for (int i = 0; i < 4; ++i) {
          const int un = i * 512 + tid;        // 2048 = 128 cols x 16 s-units
          const int colx = un >> 4;
          const int su = un & 15;
          const int hh = h0 + (colx >> 6);
          const int dd = colx & 63;
          short8 o;
          #pragma unroll
          for (int j = 0; j < 8; ++j) o[j] = (short)cbuf[(su * 8 + j) * CW + colx];
          *(short8*)(qTout + ((size_t)(bb * 16 + hh) * 64 + dd) * 1024 + s0 + su * 8) = o;
        }
      }
      __syncthreads();
    }
  } else {
    const int CWf = NF * 64 + 4;
    float* cbuf = (float*)lds;
    __syncthreads();
    #pragma unroll
    for (int p = 0; p < 2; ++p) {
      if ((w >> 2) == p) {
        #pragma unroll
        for (int m = 0; m < 8; ++m)
          #pragma unroll
          for (int n = 0; n < NF; ++n)
            #pragma unroll
            for (int r = 0; r < 4; ++r) {
              float v = (acc[m][n][r] + bv[n]) * cscale;
              if (RELU) v = fmaxf(v, 0.f);
              cbuf[(m * 16 + g4 + r) * CWf + wcN + n * 16 + lq] = v;
            }
      }
      __syncthreads();
      #pragma unroll
      for (int i = 0; i < 4 * NF; ++i) {
        const int un = i * 512 + tid;            // rows x (NF*16) float4 units
        const int row = un / (16 * NF);
        const int cu = un % (16 * NF);
        float4 v = *(const float4*)&cbuf[row * CWf + cu * 4];
        const size_t idx = (size_t)(row0 + p * 128 + row) * N + col0 + cu * 4;
        if (residual) {
          const float4 rv = *(const float4*)(residual + idx);
          v.x += rv.x; v.y += rv.y; v.z += rv.z; v.w += rv.w;
        }
        *(float4*)((float*)Cout + idx) = v;
      }
      __syncthreads();
    }
  }
}

// ---------------- flash attention v11: KVBLK=128 (two 64-halves per tile) ----
// Grid 512 x 512 thr (8 waves, 256 q-rows). One barrier/vmcnt per 128 k-rows;
// stage(t+1) covered by two half-tile compute phases. K LDS [128][64] linear;
// V LDS [2 half][64 d][64 k] subtiled so gload dests stay linear.
__global__ __launch_bounds__(512) void attn_kernel(
    const unsigned short* __restrict__ q,    // [B,S,1024] bf16 (scaled)
    const unsigned short* __restrict__ qT,   // [B*H,64,1024] bf16 (scaled)
    const int* __restrict__ mask,            // [B,1024]
    unsigned short* __restrict__ ctx) {      // [B,S,1024] bf16
  __shared__ __align__(16) unsigned short Ks[2][128 * 64];
  __shared__ __align__(16) unsigned short Vs[2][2][64 * 64];
  __shared__ int allmask;
  const int id = blockIdx.x;
  const int bh = ((id & 7) << 4) + (id >> 5);      // same-bh blocks -> same XCD
  const int qt = (id >> 3) & 3;
  const int b = bh >> 4, h = bh & 15;
  const int tid = threadIdx.x, w = tid >> 6, lane = tid & 63;
  const int lq = lane & 15;
  const int g = lane >> 4;
  const int lk8 = g * 8;
  const int swz = lane & 7;
  const int q0 = qt * 256 + w * 32;
  const size_t qbase = (size_t)b * (1024 * 1024) + h * 64;
  const size_t qTb = (size_t)bh * 64 * 1024;
  const int srow = lane >> 3;                      // 0..7
  const int su = (lane & 7) ^ srow;                // inverse-swizzled unit
  // K: wave w stages k-rows [w*16, w*16+16) of the 128-row tile (2 gloads)
  const size_t ksrc = qbase + (size_t)(w * 16 + srow) * 1024 + su * 8;
  // V: wave w stages d-rows [w*8, w*8+8) for each 64-k half (1 gload each)
  const size_t vsrc = qTb + (size_t)(w * 8 + srow) * 1024 + su * 8;
  const float RS = 2.3548202f;                     // 1/sqrt(0.125*log2e)

  auto stage = [&](int bufi, int kt) {             // kt indexes 128-row tiles
    char* Kd = (char*)Ks[bufi] + w * 2048;
    gload_lds16(q + ksrc + (size_t)(kt * 128) * 1024, Kd);
    gload_lds16(q + ksrc + (size_t)(kt * 128 + 8) * 1024, Kd + 1024);
    gload_lds16(qT + vsrc + kt * 128, (char*)Vs[bufi][0] + w * 1024);
    gload_lds16(qT + vsrc + kt * 128 + 64, (char*)Vs[bufi][1] + w * 1024);
  };

  const int* mrow = mask + b * 1024;
  // --- one-time: is the whole mask row all-ones? (uniform fast path) ---
  if (tid == 0) allmask = 1;
  int mp = 1;
  #pragma unroll
  for (int i = 0; i < 2; ++i) mp &= (mrow[tid + i * 512] != 0);
  stage(0, 0);   // overlap staging with the mask scan
  __syncthreads();                 // allmask initialized; staging issued
  if (!__all(mp) && lane == 0) atomicAnd(&allmask, 0);
  asm volatile("s_waitcnt vmcnt(0)" ::: "memory");
  __syncthreads();
  const bool fullmask = (allmask != 0);

  short8 qa[2][2];
  #pragma unroll
  for (int qf = 0; qf < 2; ++qf)
    #pragma unroll
    for (int kk = 0; kk < 2; ++kk)
      qa[qf][kk] = *(const short8*)&q[qbase + (size_t)(q0 + qf * 16 + lq) * 1024 + kk * 32 + lk8];

  short8 ones;
  #pragma unroll
  for (int i = 0; i < 8; ++i) ones[i] = (short)0x3F80;  // bf16 1.0

  f32x4 lacc[2] = {};
  f32x4 Oa[2][4];
  #pragma unroll
  for (int mf = 0; mf < 2; ++mf)
    #pragma unroll
    for (int nf = 0; nf < 4; ++nf) Oa[mf][nf] = (f32x4){0.f, 0.f, 0.f, 0.f};

  int cur = 0;

  for (int kt = 0; kt < 8; ++kt) {
    if (kt < 7) stage(cur ^ 1, kt + 1);
    #pragma unroll
    for (int hf = 0; hf < 2; ++hf) {
      const int k0 = kt * 128 + hf * 64;
      const char* Kb = (const char*)Ks[cur] + hf * 8192;
      const char* Vb = (const char*)Vs[cur][hf];
      // --- St = K Q^T (already log2-domain) ---
      f32x4 s[2][4];
      #pragma unroll
      for (int qf = 0; qf < 2; ++qf)
        #pragma unroll
        for (int kf = 0; kf < 4; ++kf) s[qf][kf] = (f32x4){0.f, 0.f, 0.f, 0.f};
      #pragma unroll
      for (int kf = 0; kf < 4; ++kf) {
        const char* kr = Kb + (kf * 16 + lq) * 128;
        const short8 ka0 = *(const short8*)(kr + (((g) ^ swz) << 4));
        const short8 ka1 = *(const short8*)(kr + (((4 + g) ^ swz) << 4));
        s[0][kf] = MFMA16(ka0, qa[0][0], s[0][kf]);
        s[0][kf] = MFMA16(ka1, qa[0][1], s[0][kf]);
        s[1][kf] = MFMA16(ka0, qa[1][0], s[1][kf]);
        s[1][kf] = MFMA16(ka1, qa[1][1], s[1][kf]);
      }
      // --- mask add (skipped when all-ones) ---
      if (!fullmask) {
        #pragma unroll
        for (int kf = 0; kf < 4; ++kf) {
          const int4 mv = *(const int4*)&mrow[k0 + kf * 16 + g * 4];
          float madd[4];
          madd[0] = mv.x ? 0.f : -1e9f; madd[1] = mv.y ? 0.f : -1e9f;
          madd[2] = mv.z ? 0.f : -1e9f; madd[3] = mv.w ? 0.f : -1e9f;
          #pragma unroll
          for (int qf = 0; qf < 2; ++qf)
            #pragma unroll
            for (int r = 0; r < 4; ++r)
              s[qf][kf][r] += madd[r];
        }
      }
      // --- P = exp2(s), pack fully in registers ---
      unsigned int E[2][4], O[2][4];
      #pragma unroll
      for (int qf = 0; qf < 2; ++qf) {
        #pragma unroll
        for (int kf = 0; kf < 4; ++kf) {
          float p0 = exp2f(s[qf][kf][0]);
          float p1 = exp2f(s[qf][kf][1]);
          float p2 = exp2f(s[qf][kf][2]);
          float p3 = exp2f(s[qf][kf][3]);
          asm("v_cvt_pk_bf16_f32 %0, %1, %2" : "=v"(E[qf][kf]) : "v"(p0), "v"(p1));
          asm("v_cvt_pk_bf16_f32 %0, %1, %2" : "=v"(O[qf][kf]) : "v"(p2), "v"(p3));
        }
      }
      // --- rearrange P to PV A-frags: permlane32_swap + permlane16_swap ---
      short8 pa[2][2];
      #pragma unroll
      for (int qf = 0; qf < 2; ++qf) {
        #pragma unroll
        for (int ks = 0; ks < 2; ++ks) {
          unsigned int e0 = E[qf][2 * ks], e1 = E[qf][2 * ks + 1];
          unsigned int o0 = O[qf][2 * ks], o1 = O[qf][2 * ks + 1];
          asm("v_permlane32_swap_b32 %0, %1" : "+v"(e0), "+v"(e1));
          asm("v_permlane16_swap_b32 %0, %1" : "+v"(e0), "+v"(e1));
          asm("v_permlane32_swap_b32 %0, %1" : "+v"(o0), "+v"(o1));
          asm("v_permlane16_swap_b32 %0, %1" : "+v"(o0), "+v"(o1));
          union { unsigned int u[4]; short8 s8; } pw;
          pw.u[0] = e0; pw.u[1] = o0; pw.u[2] = e1; pw.u[3] = o1;
          pa[qf][ks] = pw.s8;
        }
      }
      // --- O += P @ V, l += P @ ones ---
      #pragma unroll
      for (int ks = 0; ks < 2; ++ks) {
        #pragma unroll
        for (int nf = 0; nf < 4; ++nf) {
          const short8 vb = *(const short8*)(Vb + (nf * 16 + lq) * 128 + (((4 * ks + g) ^ swz) << 4));
          Oa[0][nf] = MFMA16(pa[0][ks], vb, Oa[0][nf]);
          Oa[1][nf] = MFMA16(pa[1][ks], vb, Oa[1][nf]);
        }
        lacc[0] = MFMA16(pa[0][ks], ones, lacc[0]);
        lacc[1] = MFMA16(pa[1][ks], ones, lacc[1]);
      }
    }
    __syncthreads();
    cur ^= 1;
  }
  // --- epilogue: l is per-row in lacc regs (all lanes identical) ---
  #pragma unroll
  for (int mf = 0; mf < 2; ++mf) {
    #pragma unroll
    for (int r = 0; r < 4; ++r) {
      const float linv = RS / lacc[mf][r];
      const int row = q0 + mf * 16 + g * 4 + r;
      #pragma unroll
      for (int nf = 0; nf < 4; ++nf) {
        const int col = h * 64 + nf * 16 + lq;
        ctx[((size_t)b * 1024 + row) * 1024 + col] = f2bf(Oa[mf][nf][r] * linv);
      }
    }
  }
}

// ---------------- launch ----------------------------------------------------
extern "C" void kernel_launch(void* const* d_in, const int* in_sizes, int n_in,
                              void* d_out, int out_size, void* d_ws, size_t ws_size,
                              hipStream_t stream) {
  const float* x    = (const float*)d_in[0];
  const int*   mask = (const int*)d_in[1];
  const float* wq   = (const float*)d_in[2];
  const float* bq   = (const float*)d_in[3];
  const float* wo   = (const float*)d_in[8];
  const float* bo   = (const float*)d_in[9];
  const float* w1   = (const float*)d_in[10];
  const float* b1   = (const float*)d_in[11];
  const float* w2   = (const float*)d_in[12];
  const float* b2   = (const float*)d_in[13];
  const float* ln1a = (const float*)d_in[14];
  const float* ln1b = (const float*)d_in[15];
  const float* ln2a = (const float*)d_in[16];
  const float* ln2b = (const float*)d_in[17];
  float* out = (float*)d_out;

  char* ws = (char*)d_ws;
  unsigned short* wq_b  = (unsigned short*)(ws);                  //  2 MB
  unsigned short* wo_b  = (unsigned short*)(ws + (2l << 20));     //  2 MB
  unsigned short* w1_b  = (unsigned short*)(ws + (4l << 20));     //  8 MB
  unsigned short* w2_b  = (unsigned short*)(ws + (12l << 20));    //  8 MB
  unsigned short* n_b   = (unsigned short*)(ws + (20l << 20));    // 16 MB (n, then n2)
  unsigned short* q_b   = (unsigned short*)(ws + (36l << 20));    // 16 MB
  unsigned short* qT_b  = (unsigned short*)(ws + (52l << 20));    // 16 MB
  unsigned short* ctx_b = (unsigned short*)(ws + (68l << 20));    // 16 MB
  unsigned short* h_b   = (unsigned short*)(ws + (84l << 20));    // 64 MB

  const float SQRT_SC = 0.42466090f;  // sqrt(0.125 * log2(e))

  CvtArgs ca{wq, wo, w1, w2, wq_b, wo_b, w1_b, w2_b};
  // fused LN1 (8192 blocks) + weight cvt (10240 blocks)
  cvt_ln<<<18432, 256, 0, stream>>>(ca, x, ln1a, ln1b, n_b);
  // Q-proj: 256x128 tiles, grid 256, scaled, fused qT transpose
  gemm2ph<1, 0, 2, 1, 1><<<256, 512, 0, stream>>>(n_b, 1024, wq_b, 1024, bq, nullptr, q_b, qT_b, 8192, 1024, 1024, SQRT_SC, 8);
  attn_kernel<<<512, 512, 0, stream>>>(q_b, qT_b, mask, ctx_b);
  // O-proj + residual(x): fp32 out, LDS-staged epilogue
  gemm2ph<0, 0, 2, 0, 1><<<256, 512, 0, stream>>>(ctx_b, 1024, wo_b, 1024, bo, x, out, nullptr, 8192, 1024, 1024, 1.0f, 8);
  ln_kernel<<<8192, 256, 0, stream>>>(out, ln2a, ln2b, n_b);
  // FFN1: 256x256 tile, grid 512, double-buffered (champion config)
  gemm2ph<1, 1, 4, 0, 1><<<512, 512, 0, stream>>>(n_b, 1024, w1_b, 1024, b1, nullptr, h_b, nullptr, 8192, 4096, 1024, 1.0f, 16);
  // FFN2: 256x128 tile, grid 256, double-buffered
  gemm2ph<0, 0, 2, 0, 1><<<256, 512, 0, stream>>>(h_b, 4096, w2_b, 4096, b2, out, out, nullptr, 8192, 1024, 4096, 1.0f, 8);
}